// Round 2
// 381.357 us; speedup vs baseline: 1.1606x; 1.1606x over previous
//
#include <hip/hip_runtime.h>
#include <cstdint>
#include <cstddef>

#define EPSV 1e-5f
#define TEMP_MINV 0.01f

typedef __attribute__((ext_vector_type(8))) short bf16x8;
typedef __attribute__((ext_vector_type(4))) float f32x4;

__device__ inline short f2bf(float f) {
    unsigned u = __float_as_uint(f);
    unsigned r = (u + 0x7fffu + ((u >> 16) & 1u)) >> 16;
    return (short)r;
}

__device__ inline void gload16(const void* g, void* l) {
    __builtin_amdgcn_global_load_lds(
        (const __attribute__((address_space(1))) void*)g,
        (__attribute__((address_space(3))) void*)l, 16, 0, 0);
}

// ---------------- flags: flags[l]=1 means residual entering level l is exactly 0 ----------------
__global__ void flags_kernel(const float* __restrict__ scales, int L, int* __restrict__ flags) {
    if (threadIdx.x == 0 && blockIdx.x == 0) {
        int zero = 0;
        for (int l = 0; l < L; ++l) {
            flags[l] = zero;
            if (scales[l] == 1.0f) zero = 1;
        }
    }
}

// ---- pack 32 rows of fp32 [R][512] -> bf16 packed [64][R][8] (one 256-thread block) ----
__device__ inline void pack_block(const float* __restrict__ in, short* __restrict__ outp,
                                  int R, int rb, short* lds) {
    const int t = threadIdx.x;
    const float4* in4 = (const float4*)(in + (size_t)rb * 512);
    #pragma unroll
    for (int it = 0; it < 16; ++it) {
        const int flat = it * 1024 + t * 4;
        float4 v = in4[flat >> 2];
        const int row = flat >> 9, col = flat & 511;
        short4 o; o.x = f2bf(v.x); o.y = f2bf(v.y); o.z = f2bf(v.z); o.w = f2bf(v.w);
        *(short4*)&lds[row * 520 + col] = o;
    }
    __syncthreads();
    #pragma unroll
    for (int it = 0; it < 8; ++it) {
        const int c = it * 256 + t;
        const int kb = c >> 5, r = c & 31;
        int4 v = *(const int4*)&lds[r * 520 + kb * 8];
        *(int4*)(outp + ((size_t)kb * R + rb + r) * 8) = v;
    }
}

// same, but applies the residual recurrence through level l then scales by scales[l]
__device__ inline void pack_block_rec(const float* __restrict__ in, short* __restrict__ outp,
                                      int R, int rb, short* lds,
                                      const float* __restrict__ scales, int l) {
    const int t = threadIdx.x;
    const float4* in4 = (const float4*)(in + (size_t)rb * 512);
    #pragma unroll
    for (int it = 0; it < 16; ++it) {
        const int flat = it * 1024 + t * 4;
        float4 v = in4[flat >> 2];
        float e[4] = {v.x, v.y, v.z, v.w};
        for (int j = 0; j < l; ++j) {
            const float sc = scales[j];
            #pragma unroll
            for (int q = 0; q < 4; ++q) { float rv = e[q] * sc; e[q] = e[q] - rv / sc; }
        }
        const float sl = scales[l];
        const int row = flat >> 9, col = flat & 511;
        short4 o;
        o.x = f2bf(e[0] * sl); o.y = f2bf(e[1] * sl);
        o.z = f2bf(e[2] * sl); o.w = f2bf(e[3] * sl);
        *(short4*)&lds[row * 520 + col] = o;
    }
    __syncthreads();
    #pragma unroll
    for (int it = 0; it < 8; ++it) {
        const int c = it * 256 + t;
        const int kb = c >> 5, r = c & 31;
        int4 v = *(const int4*)&lds[r * 520 + kb * 8];
        *(int4*)(outp + ((size_t)kb * R + rb + r) * 8) = v;
    }
}

// ---------------- merged input prep: pack features | pack W | pack cb level 0 | cb row norms ----------------
__global__ __launch_bounds__(256) void prep_inputs(
    const float* __restrict__ features, const float* __restrict__ W,
    const float* __restrict__ cb,
    short* __restrict__ P1, short* __restrict__ Wp, short* __restrict__ cbp,
    float* __restrict__ cn, int M, int D, int K, int LK) {
    __shared__ __align__(16) short lds[32 * 520];
    int gid = blockIdx.x;
    const int nF = M / 32, nW = D / 32, nC = K / 32;
    if (gid < nF) { pack_block(features, P1, M, gid * 32, lds); return; }
    gid -= nF;
    if (gid < nW) { pack_block(W, Wp, D, gid * 32, lds); return; }
    gid -= nW;
    if (gid < nC) { pack_block(cb, cbp, K, gid * 32, lds); return; }
    gid -= nC;
    // codebook row squared norms, 4 rows per block (wave per row)
    const int wv = threadIdx.x >> 6, lane = threadIdx.x & 63;
    const int row = gid * 4 + wv;
    if (row >= LK) return;
    const float* p = cb + (size_t)row * 512;
    float s = 0.f;
    for (int j = lane; j < 512; j += 64) { float v = p[j]; s += v * v; }
    #pragma unroll
    for (int off = 32; off; off >>= 1) s += __shfl_down(s, off);
    if (lane == 0) cn[row] = s;
}

// ---------------- GEMM1 (MFMA): y[M,N] = A[M,Kd] @ W[N,Kd]^T + bias ----------------
__global__ __launch_bounds__(256) void gemm1_mfma(
    const short* __restrict__ Ap, const short* __restrict__ Bp,
    const float* __restrict__ bias, float* __restrict__ Y,
    int M, int N, int Kd) {
    __shared__ __align__(16) short As[8 * 128 * 8];
    __shared__ __align__(16) short Bs[8 * 128 * 8];
    const int r0 = blockIdx.x * 128, c0 = blockIdx.y * 128;
    const int lane = threadIdx.x & 63, w = threadIdx.x >> 6;
    const int wm = (w & 1) << 6, wn = (w >> 1) << 6;
    const int fr = lane & 15, fo = lane >> 4;
    f32x4 acc[4][4];
    #pragma unroll
    for (int a = 0; a < 4; ++a)
        #pragma unroll
        for (int b = 0; b < 4; ++b) acc[a][b] = (f32x4){0.f, 0.f, 0.f, 0.f};
    for (int k0 = 0; k0 < Kd; k0 += 64) {
        const int kb0 = k0 >> 3;
        __syncthreads();
        #pragma unroll
        for (int sidx = 0; sidx < 2; ++sidx) {
            const int kblk = (w << 1) + sidx;
            const short* ga = Ap + ((size_t)(kb0 + kblk) * M + r0) * 8;
            const short* gb = Bp + ((size_t)(kb0 + kblk) * N + c0) * 8;
            short* la = &As[kblk * 128 * 8];
            short* lb = &Bs[kblk * 128 * 8];
            #pragma unroll
            for (int h = 0; h < 2; ++h) {
                gload16(ga + ((h << 6) + lane) * 8, la + (h << 6) * 8);
                gload16(gb + ((h << 6) + lane) * 8, lb + (h << 6) * 8);
            }
        }
        __syncthreads();
        #pragma unroll
        for (int s = 0; s < 2; ++s) {
            const int kb = (s << 2) + fo;
            bf16x8 af[4], bfv[4];
            #pragma unroll
            for (int mt = 0; mt < 4; ++mt)
                af[mt] = *(const bf16x8*)&As[(kb * 128 + wm + mt * 16 + fr) * 8];
            #pragma unroll
            for (int nt = 0; nt < 4; ++nt)
                bfv[nt] = *(const bf16x8*)&Bs[(kb * 128 + wn + nt * 16 + fr) * 8];
            #pragma unroll
            for (int mt = 0; mt < 4; ++mt)
                #pragma unroll
                for (int nt = 0; nt < 4; ++nt)
                    acc[mt][nt] = __builtin_amdgcn_mfma_f32_16x16x32_bf16(af[mt], bfv[nt], acc[mt][nt], 0, 0, 0);
        }
    }
    #pragma unroll
    for (int mt = 0; mt < 4; ++mt) {
        #pragma unroll
        for (int reg = 0; reg < 4; ++reg) {
            const int r = r0 + wm + mt * 16 + (fo << 2) + reg;
            float* orow = Y + (size_t)r * N;
            #pragma unroll
            for (int nt = 0; nt < 4; ++nt) {
                const int c = c0 + wn + nt * 16 + fr;
                orow[c] = acc[mt][nt][reg] + bias[c];
            }
        }
    }
}

// ---------------- fused epilogue: LN(affine)+ReLU -> x ; rs0 pack -> P1 ; ||rs0||^2 ;
//                  qsum recurrence ; LN(qsum) -> out_ln.  One wave per row, 4 rows/block.
__global__ __launch_bounds__(256) void fused_epi(
    const float* __restrict__ Yin, float* __restrict__ Xout,
    short* __restrict__ P1, float* __restrict__ rsn, float* __restrict__ outln,
    const float* __restrict__ g, const float* __restrict__ b,
    const float* __restrict__ scales, const int* __restrict__ flags,
    int M, int L) {
    __shared__ __align__(16) short plds[4 * 520];
    const int lane = threadIdx.x & 63, wv = threadIdx.x >> 6;
    const int rb = blockIdx.x * 4;
    const int r = rb + wv;
    const float* p = Yin + (size_t)r * 512 + lane * 8;
    float4 v0 = *(const float4*)p;
    float4 v1 = *(const float4*)(p + 4);
    float e[8] = {v0.x, v0.y, v0.z, v0.w, v1.x, v1.y, v1.z, v1.w};
    // mean
    float s = 0.f;
    #pragma unroll
    for (int j = 0; j < 8; ++j) s += e[j];
    #pragma unroll
    for (int off = 1; off < 64; off <<= 1) s += __shfl_xor(s, off);
    const float mu = s * (1.0f / 512.0f);
    // variance
    float vs = 0.f;
    #pragma unroll
    for (int j = 0; j < 8; ++j) { float d = e[j] - mu; vs += d * d; }
    #pragma unroll
    for (int off = 1; off < 64; off <<= 1) vs += __shfl_xor(vs, off);
    const float inv = rsqrtf(vs * (1.0f / 512.0f) + EPSV);
    // affine + relu
    float4 g0 = *(const float4*)(g + lane * 8);
    float4 g1 = *(const float4*)(g + lane * 8 + 4);
    float4 b0 = *(const float4*)(b + lane * 8);
    float4 b1 = *(const float4*)(b + lane * 8 + 4);
    float gg[8] = {g0.x, g0.y, g0.z, g0.w, g1.x, g1.y, g1.z, g1.w};
    float bb[8] = {b0.x, b0.y, b0.z, b0.w, b1.x, b1.y, b1.z, b1.w};
    float x8[8];
    #pragma unroll
    for (int j = 0; j < 8; ++j) x8[j] = fmaxf((e[j] - mu) * inv * gg[j] + bb[j], 0.0f);
    // write x only if some later level actually needs it (generic path)
    bool needX = false;
    for (int l = 1; l < L; ++l) needX |= (flags[l] == 0);
    if (needX) {
        float* q = Xout + (size_t)r * 512 + lane * 8;
        *(float4*)q = make_float4(x8[0], x8[1], x8[2], x8[3]);
        *(float4*)(q + 4) = make_float4(x8[4], x8[5], x8[6], x8[7]);
    }
    // rs0 = x * scales[0]; squared norm + bf16 pack (level 0 has no recurrence -> always exact)
    const float s0 = scales[0];
    float rs8[8]; float rn = 0.f;
    #pragma unroll
    for (int j = 0; j < 8; ++j) { rs8[j] = x8[j] * s0; rn += rs8[j] * rs8[j]; }
    #pragma unroll
    for (int off = 1; off < 64; off <<= 1) rn += __shfl_xor(rn, off);
    if (lane == 0) rsn[r] = rn;
    short4 pa, pb;
    pa.x = f2bf(rs8[0]); pa.y = f2bf(rs8[1]); pa.z = f2bf(rs8[2]); pa.w = f2bf(rs8[3]);
    pb.x = f2bf(rs8[4]); pb.y = f2bf(rs8[5]); pb.z = f2bf(rs8[6]); pb.w = f2bf(rs8[7]);
    *(short4*)&plds[wv * 520 + lane * 8] = pa;
    *(short4*)&plds[wv * 520 + lane * 8 + 4] = pb;
    // qsum recurrence (level-outer so scales indexing is scalar loads, no scratch arrays)
    float q8[8], r8[8];
    #pragma unroll
    for (int j = 0; j < 8; ++j) { q8[j] = 0.f; r8[j] = x8[j]; }
    for (int l = 0; l < L; ++l) {
        const float sc = scales[l];
        #pragma unroll
        for (int j = 0; j < 8; ++j) { float rv = r8[j] * sc; q8[j] += rv; r8[j] -= rv / sc; }
    }
    // LN(qsum), no affine
    float s2 = 0.f;
    #pragma unroll
    for (int j = 0; j < 8; ++j) s2 += q8[j];
    #pragma unroll
    for (int off = 1; off < 64; off <<= 1) s2 += __shfl_xor(s2, off);
    const float mu2 = s2 * (1.0f / 512.0f);
    float v2 = 0.f;
    #pragma unroll
    for (int j = 0; j < 8; ++j) { float d = q8[j] - mu2; v2 += d * d; }
    #pragma unroll
    for (int off = 1; off < 64; off <<= 1) v2 += __shfl_xor(v2, off);
    const float inv2 = rsqrtf(v2 * (1.0f / 512.0f) + EPSV);
    float* q = outln + (size_t)r * 512 + lane * 8;
    *(float4*)q = make_float4((q8[0] - mu2) * inv2, (q8[1] - mu2) * inv2,
                              (q8[2] - mu2) * inv2, (q8[3] - mu2) * inv2);
    *(float4*)(q + 4) = make_float4((q8[4] - mu2) * inv2, (q8[5] - mu2) * inv2,
                                    (q8[6] - mu2) * inv2, (q8[7] - mu2) * inv2);
    // coalesced-ish P1 writeout: 64B runs per k-group across the block's 4 rows
    __syncthreads();
    {
        const int t = threadIdx.x;
        const int kb = t >> 2, rr = t & 3;
        int4 v = *(const int4*)&plds[rr * 520 + kb * 8];
        *(int4*)(P1 + ((size_t)kb * M + rb + rr) * 8) = v;
    }
}

// ---------------- gated generic-path prep for level l>=1: pack cb | pack x (recurrence) | rsnorm ----------------
__global__ __launch_bounds__(256) void prep_level(
    const float* __restrict__ x, const float* __restrict__ cb_l,
    const float* __restrict__ scales, const int* __restrict__ flags, int l,
    short* __restrict__ cbp, short* __restrict__ P1, float* __restrict__ rsn,
    int M, int K) {
    if (flags[l]) return;
    __shared__ __align__(16) short lds[32 * 520];
    int gid = blockIdx.x;
    const int nC = K / 32, nX = M / 32;
    if (gid < nC) { pack_block(cb_l, cbp, K, gid * 32, lds); return; }
    gid -= nC;
    if (gid < nX) { pack_block_rec(x, P1, M, gid * 32, lds, scales, l); return; }
    gid -= nX;
    const int wv = threadIdx.x >> 6, lane = threadIdx.x & 63;
    const int row = gid * 4 + wv;
    if (row >= M) return;
    const float* p = x + (size_t)row * 512;
    float s = 0.f;
    for (int j = lane; j < 512; j += 64) {
        float r_ = p[j];
        for (int q = 0; q < l; ++q) { float sc = scales[q]; float rv = r_ * sc; r_ -= rv / sc; }
        r_ *= scales[l];
        s += r_ * r_;
    }
    #pragma unroll
    for (int off = 32; off; off >>= 1) s += __shfl_down(s, off);
    if (lane == 0) rsn[row] = s;
}

// ---------------- dist (MFMA + flagged-level broadcast merged into one launch) ----------------
// mode 0: grid.y spans all L*K columns. Level-0 blocks (dispatched first) do the GEMM;
//         flagged-level blocks broadcast -cn/temp (pure write, overlaps with the GEMM);
//         unflagged level>=1 blocks return (handled by their own later launch).
// mode l>=1: grid.y spans K columns; compute only if !flags[l].
__global__ __launch_bounds__(256) void dist_mfma(
    const short* __restrict__ Ap, const short* __restrict__ Bp,
    const float* __restrict__ rsn, const float* __restrict__ cn,
    const float* __restrict__ temp_p, const int* __restrict__ flags,
    float* __restrict__ out, int M, int K, int Kd, int LK, int mode) {
    __shared__ __align__(16) short As[8 * 128 * 8];
    __shared__ __align__(16) short Bs[8 * 128 * 8];
    const int r0 = blockIdx.x * 128;
    int cg0, cl0;
    if (mode == 0) {
        cg0 = blockIdx.y * 128;
        const int lvl = cg0 / K;
        if (lvl != 0) {
            if (!flags[lvl]) return;
            const float inv_t = 1.0f / fmaxf(temp_p[0], TEMP_MINV);
            const int tc = (threadIdx.x & 31) << 2, tr = threadIdx.x >> 5;
            float4 cv = *(const float4*)(cn + cg0 + tc);
            float4 v = make_float4(-cv.x * inv_t, -cv.y * inv_t, -cv.z * inv_t, -cv.w * inv_t);
            #pragma unroll
            for (int i = 0; i < 16; ++i) {
                const int r = r0 + i * 8 + tr;
                *(float4*)(out + (size_t)r * LK + cg0 + tc) = v;
            }
            return;
        }
        cl0 = cg0;
    } else {
        if (flags[mode]) return;
        cl0 = blockIdx.y * 128;
        cg0 = mode * K + cl0;
    }
    const float inv_t = 1.0f / fmaxf(temp_p[0], TEMP_MINV);
    const int lane = threadIdx.x & 63, w = threadIdx.x >> 6;
    const int wm = (w & 1) << 6, wn = (w >> 1) << 6;
    const int fr = lane & 15, fo = lane >> 4;
    f32x4 acc[4][4];
    #pragma unroll
    for (int a = 0; a < 4; ++a)
        #pragma unroll
        for (int b = 0; b < 4; ++b) acc[a][b] = (f32x4){0.f, 0.f, 0.f, 0.f};
    for (int k0 = 0; k0 < Kd; k0 += 64) {
        const int kb0 = k0 >> 3;
        __syncthreads();
        #pragma unroll
        for (int sidx = 0; sidx < 2; ++sidx) {
            const int kblk = (w << 1) + sidx;
            const short* ga = Ap + ((size_t)(kb0 + kblk) * M + r0) * 8;
            const short* gb = Bp + ((size_t)(kb0 + kblk) * K + cl0) * 8;
            short* la = &As[kblk * 128 * 8];
            short* lb = &Bs[kblk * 128 * 8];
            #pragma unroll
            for (int h = 0; h < 2; ++h) {
                gload16(ga + ((h << 6) + lane) * 8, la + (h << 6) * 8);
                gload16(gb + ((h << 6) + lane) * 8, lb + (h << 6) * 8);
            }
        }
        __syncthreads();
        #pragma unroll
        for (int s = 0; s < 2; ++s) {
            const int kb = (s << 2) + fo;
            bf16x8 af[4], bfv[4];
            #pragma unroll
            for (int mt = 0; mt < 4; ++mt)
                af[mt] = *(const bf16x8*)&As[(kb * 128 + wm + mt * 16 + fr) * 8];
            #pragma unroll
            for (int nt = 0; nt < 4; ++nt)
                bfv[nt] = *(const bf16x8*)&Bs[(kb * 128 + wn + nt * 16 + fr) * 8];
            #pragma unroll
            for (int mt = 0; mt < 4; ++mt)
                #pragma unroll
                for (int nt = 0; nt < 4; ++nt)
                    acc[mt][nt] = __builtin_amdgcn_mfma_f32_16x16x32_bf16(af[mt], bfv[nt], acc[mt][nt], 0, 0, 0);
        }
    }
    #pragma unroll
    for (int mt = 0; mt < 4; ++mt) {
        #pragma unroll
        for (int reg = 0; reg < 4; ++reg) {
            const int r = r0 + wm + mt * 16 + (fo << 2) + reg;
            const float rn = rsn[r];
            float* orow = out + (size_t)r * LK;
            #pragma unroll
            for (int nt = 0; nt < 4; ++nt) {
                const int c = cg0 + wn + nt * 16 + fr;
                orow[c] = -(rn + cn[c] - 2.0f * acc[mt][nt][reg]) * inv_t;
            }
        }
    }
}

extern "C" void kernel_launch(void* const* d_in, const int* in_sizes, int n_in,
                              void* d_out, int out_size, void* d_ws, size_t ws_size,
                              hipStream_t stream) {
    const float* features = (const float*)d_in[0];
    const float* W        = (const float*)d_in[1];
    const float* bproj    = (const float*)d_in[2];
    const float* lng      = (const float*)d_in[3];
    const float* lnb      = (const float*)d_in[4];
    const float* cb       = (const float*)d_in[5];
    const float* scales   = (const float*)d_in[6];
    const float* temp     = (const float*)d_in[7];

    const int D = in_sizes[2];            // 512
    const int M = in_sizes[0] / D;        // 8192
    const int L = in_sizes[6];            // 4
    const int K = in_sizes[5] / (L * D);  // 2048
    const int LK = L * K;

    float* out    = (float*)d_out;                 // [M, L*K]
    float* out_ln = out + (size_t)M * LK;          // [M, D]

    // workspace (floats): x[M*D] | y[M*D] | P1 (M*D bf16) | Wp (D*D bf16) | cbp (K*D bf16)
    //                     | rsn[M] | cn[L*K] | flags
    float* ws = (float*)d_ws;
    float* x  = ws;
    float* y  = x + (size_t)M * D;
    short* P1 = (short*)(y + (size_t)M * D);
    float* aP1 = y + (size_t)M * D + (size_t)M * D / 2;
    short* Wp = (short*)aP1;
    float* aWp = aP1 + (size_t)D * D / 2;
    short* cbp = (short*)aWp;
    float* rsn = aWp + (size_t)K * D / 2;
    float* cn  = rsn + M;
    int* flags = (int*)(cn + (size_t)LK);

    flags_kernel<<<1, 64, 0, stream>>>(scales, L, flags);

    // all input packing + codebook norms in one launch
    const int nPrep = M / 32 + D / 32 + K / 32 + (LK + 3) / 4;
    prep_inputs<<<nPrep, 256, 0, stream>>>(features, W, cb, P1, Wp, cbp, cn, M, D, K, LK);

    // y = features @ W^T + b
    gemm1_mfma<<<dim3(M / 128, D / 128), 256, 0, stream>>>(P1, Wp, bproj, y, M, D, D);

    // LN+ReLU -> x, rs0 pack -> P1, ||rs0||^2 -> rsn, qsum -> LN -> out_ln
    fused_epi<<<M / 4, 256, 0, stream>>>(y, x, P1, rsn, out_ln, lng, lnb, scales, flags, M, L);

    // level-0 GEMM + all flagged-level broadcasts in one launch (compute blocks dispatch first)
    dist_mfma<<<dim3(M / 128, LK / 128), 256, 0, stream>>>(P1, cbp, rsn, cn, temp, flags,
                                                           out, M, K, D, LK, 0);

    // generic path for non-unit scales: gated, no-ops when flagged
    for (int l = 1; l < L; ++l) {
        const int nPl = K / 32 + M / 32 + M / 4;
        prep_level<<<nPl, 256, 0, stream>>>(x, cb + (size_t)l * K * D, scales, flags, l,
                                            cbp, P1, rsn, M, K);
        dist_mfma<<<dim3(M / 128, K / 128), 256, 0, stream>>>(P1, cbp, rsn, cn, temp, flags,
                                                              out, M, K, D, LK, l);
    }
}

// Round 3
// 376.676 us; speedup vs baseline: 1.1750x; 1.0124x over previous
//
#include <hip/hip_runtime.h>
#include <cstdint>
#include <cstddef>

#define EPSV 1e-5f
#define TEMP_MINV 0.01f

typedef __attribute__((ext_vector_type(8))) short bf16x8;
typedef __attribute__((ext_vector_type(4))) float f32x4;

__device__ inline short f2bf(float f) {
    unsigned u = __float_as_uint(f);
    unsigned r = (u + 0x7fffu + ((u >> 16) & 1u)) >> 16;
    return (short)r;
}

__device__ inline void gload16(const void* g, void* l) {
    __builtin_amdgcn_global_load_lds(
        (const __attribute__((address_space(1))) void*)g,
        (__attribute__((address_space(3))) void*)l, 16, 0, 0);
}

// ---------------- flags: flags[l]=1 means residual entering level l is exactly 0 ----------------
__global__ void flags_kernel(const float* __restrict__ scales, int L, int* __restrict__ flags) {
    if (threadIdx.x == 0 && blockIdx.x == 0) {
        int zero = 0;
        for (int l = 0; l < L; ++l) {
            flags[l] = zero;
            if (scales[l] == 1.0f) zero = 1;
        }
    }
}

// ---- pack 32 rows of fp32 [R][512] -> bf16 packed [64][R][8] (one 256-thread block) ----
__device__ inline void pack_block(const float* __restrict__ in, short* __restrict__ outp,
                                  int R, int rb, short* lds) {
    const int t = threadIdx.x;
    const float4* in4 = (const float4*)(in + (size_t)rb * 512);
    #pragma unroll
    for (int it = 0; it < 16; ++it) {
        const int flat = it * 1024 + t * 4;
        float4 v = in4[flat >> 2];
        const int row = flat >> 9, col = flat & 511;
        short4 o; o.x = f2bf(v.x); o.y = f2bf(v.y); o.z = f2bf(v.z); o.w = f2bf(v.w);
        *(short4*)&lds[row * 520 + col] = o;
    }
    __syncthreads();
    #pragma unroll
    for (int it = 0; it < 8; ++it) {
        const int c = it * 256 + t;
        const int kb = c >> 5, r = c & 31;
        int4 v = *(const int4*)&lds[r * 520 + kb * 8];
        *(int4*)(outp + ((size_t)kb * R + rb + r) * 8) = v;
    }
}

// same, but applies the residual recurrence through level l then scales by scales[l]
__device__ inline void pack_block_rec(const float* __restrict__ in, short* __restrict__ outp,
                                      int R, int rb, short* lds,
                                      const float* __restrict__ scales, int l) {
    const int t = threadIdx.x;
    const float4* in4 = (const float4*)(in + (size_t)rb * 512);
    #pragma unroll
    for (int it = 0; it < 16; ++it) {
        const int flat = it * 1024 + t * 4;
        float4 v = in4[flat >> 2];
        float e[4] = {v.x, v.y, v.z, v.w};
        for (int j = 0; j < l; ++j) {
            const float sc = scales[j];
            #pragma unroll
            for (int q = 0; q < 4; ++q) { float rv = e[q] * sc; e[q] = e[q] - rv / sc; }
        }
        const float sl = scales[l];
        const int row = flat >> 9, col = flat & 511;
        short4 o;
        o.x = f2bf(e[0] * sl); o.y = f2bf(e[1] * sl);
        o.z = f2bf(e[2] * sl); o.w = f2bf(e[3] * sl);
        *(short4*)&lds[row * 520 + col] = o;
    }
    __syncthreads();
    #pragma unroll
    for (int it = 0; it < 8; ++it) {
        const int c = it * 256 + t;
        const int kb = c >> 5, r = c & 31;
        int4 v = *(const int4*)&lds[r * 520 + kb * 8];
        *(int4*)(outp + ((size_t)kb * R + rb + r) * 8) = v;
    }
}

// ---------------- merged input prep: pack features | pack W | pack cb level 0 | cb row norms ----------------
__global__ __launch_bounds__(256) void prep_inputs(
    const float* __restrict__ features, const float* __restrict__ W,
    const float* __restrict__ cb,
    short* __restrict__ P1, short* __restrict__ Wp, short* __restrict__ cbp,
    float* __restrict__ cn, int M, int D, int K, int LK) {
    __shared__ __align__(16) short lds[32 * 520];
    int gid = blockIdx.x;
    const int nF = M / 32, nW = D / 32, nC = K / 32;
    if (gid < nF) { pack_block(features, P1, M, gid * 32, lds); return; }
    gid -= nF;
    if (gid < nW) { pack_block(W, Wp, D, gid * 32, lds); return; }
    gid -= nW;
    if (gid < nC) { pack_block(cb, cbp, K, gid * 32, lds); return; }
    gid -= nC;
    // codebook row squared norms, 4 rows per block (wave per row)
    const int wv = threadIdx.x >> 6, lane = threadIdx.x & 63;
    const int row = gid * 4 + wv;
    if (row >= LK) return;
    const float* p = cb + (size_t)row * 512;
    float s = 0.f;
    for (int j = lane; j < 512; j += 64) { float v = p[j]; s += v * v; }
    #pragma unroll
    for (int off = 32; off; off >>= 1) s += __shfl_down(s, off);
    if (lane == 0) cn[row] = s;
}

// ---------------- GEMM1 (MFMA) + flagged-level broadcast piggyback ----------------
// y-blocks [0, N/128): y[M,N] = A[M,Kd] @ W[N,Kd]^T + bias  (dispatched first)
// y-blocks beyond:     broadcast -cn/temp into flagged levels' logits (pure write,
//                      overlaps the GEMM's idle CU slots / spare write BW)
__global__ __launch_bounds__(256) void gemm1_mfma(
    const short* __restrict__ Ap, const short* __restrict__ Bp,
    const float* __restrict__ bias, float* __restrict__ Y,
    const float* __restrict__ cn, const float* __restrict__ temp_p,
    const int* __restrict__ flags, float* __restrict__ out,
    int M, int N, int Kd, int K, int LK) {
    __shared__ __align__(16) short As[8 * 128 * 8];
    __shared__ __align__(16) short Bs[8 * 128 * 8];
    const int by = blockIdx.y, nyG = N >> 7;
    if (by >= nyG) {
        const int bcg = by - nyG;
        const int G = K >> 7;
        const int lvl = 1 + bcg / G;
        if (!flags[lvl]) return;          // unflagged level handled by distL
        const int cg0 = lvl * K + (bcg % G) * 128;
        const float inv_t = 1.0f / fmaxf(temp_p[0], TEMP_MINV);
        const int r0 = blockIdx.x * 128;
        const int tc = (threadIdx.x & 31) << 2, tr = threadIdx.x >> 5;
        float4 cv = *(const float4*)(cn + cg0 + tc);
        float4 v = make_float4(-cv.x * inv_t, -cv.y * inv_t, -cv.z * inv_t, -cv.w * inv_t);
        #pragma unroll
        for (int i = 0; i < 16; ++i) {
            const int r = r0 + i * 8 + tr;
            *(float4*)(out + (size_t)r * LK + cg0 + tc) = v;
        }
        return;
    }
    const int r0 = blockIdx.x * 128, c0 = by * 128;
    const int lane = threadIdx.x & 63, w = threadIdx.x >> 6;
    const int wm = (w & 1) << 6, wn = (w >> 1) << 6;
    const int fr = lane & 15, fo = lane >> 4;
    f32x4 acc[4][4];
    #pragma unroll
    for (int a = 0; a < 4; ++a)
        #pragma unroll
        for (int b = 0; b < 4; ++b) acc[a][b] = (f32x4){0.f, 0.f, 0.f, 0.f};
    for (int k0 = 0; k0 < Kd; k0 += 64) {
        const int kb0 = k0 >> 3;
        __syncthreads();
        #pragma unroll
        for (int sidx = 0; sidx < 2; ++sidx) {
            const int kblk = (w << 1) + sidx;
            const short* ga = Ap + ((size_t)(kb0 + kblk) * M + r0) * 8;
            const short* gb = Bp + ((size_t)(kb0 + kblk) * N + c0) * 8;
            short* la = &As[kblk * 128 * 8];
            short* lb = &Bs[kblk * 128 * 8];
            #pragma unroll
            for (int h = 0; h < 2; ++h) {
                gload16(ga + ((h << 6) + lane) * 8, la + (h << 6) * 8);
                gload16(gb + ((h << 6) + lane) * 8, lb + (h << 6) * 8);
            }
        }
        __syncthreads();
        #pragma unroll
        for (int s = 0; s < 2; ++s) {
            const int kb = (s << 2) + fo;
            bf16x8 af[4], bfv[4];
            #pragma unroll
            for (int mt = 0; mt < 4; ++mt)
                af[mt] = *(const bf16x8*)&As[(kb * 128 + wm + mt * 16 + fr) * 8];
            #pragma unroll
            for (int nt = 0; nt < 4; ++nt)
                bfv[nt] = *(const bf16x8*)&Bs[(kb * 128 + wn + nt * 16 + fr) * 8];
            #pragma unroll
            for (int mt = 0; mt < 4; ++mt)
                #pragma unroll
                for (int nt = 0; nt < 4; ++nt)
                    acc[mt][nt] = __builtin_amdgcn_mfma_f32_16x16x32_bf16(af[mt], bfv[nt], acc[mt][nt], 0, 0, 0);
        }
    }
    #pragma unroll
    for (int mt = 0; mt < 4; ++mt) {
        #pragma unroll
        for (int reg = 0; reg < 4; ++reg) {
            const int r = r0 + wm + mt * 16 + (fo << 2) + reg;
            float* orow = Y + (size_t)r * N;
            #pragma unroll
            for (int nt = 0; nt < 4; ++nt) {
                const int c = c0 + wn + nt * 16 + fr;
                orow[c] = acc[mt][nt][reg] + bias[c];
            }
        }
    }
}

// ---------------- fused epilogue: LN(affine)+ReLU -> x ; rs0 pack -> P1 ; ||rs0||^2 ;
//                  qsum recurrence ; LN(qsum) -> out_ln.  One wave per row, 4 rows/block.
__global__ __launch_bounds__(256) void fused_epi(
    const float* __restrict__ Yin, float* __restrict__ Xout,
    short* __restrict__ P1, float* __restrict__ rsn, float* __restrict__ outln,
    const float* __restrict__ g, const float* __restrict__ b,
    const float* __restrict__ scales, const int* __restrict__ flags,
    int M, int L) {
    __shared__ __align__(16) short plds[4 * 520];
    const int lane = threadIdx.x & 63, wv = threadIdx.x >> 6;
    const int rb = blockIdx.x * 4;
    const int r = rb + wv;
    const float* p = Yin + (size_t)r * 512 + lane * 8;
    float4 v0 = *(const float4*)p;
    float4 v1 = *(const float4*)(p + 4);
    float e[8] = {v0.x, v0.y, v0.z, v0.w, v1.x, v1.y, v1.z, v1.w};
    float s = 0.f;
    #pragma unroll
    for (int j = 0; j < 8; ++j) s += e[j];
    #pragma unroll
    for (int off = 1; off < 64; off <<= 1) s += __shfl_xor(s, off);
    const float mu = s * (1.0f / 512.0f);
    float vs = 0.f;
    #pragma unroll
    for (int j = 0; j < 8; ++j) { float d = e[j] - mu; vs += d * d; }
    #pragma unroll
    for (int off = 1; off < 64; off <<= 1) vs += __shfl_xor(vs, off);
    const float inv = rsqrtf(vs * (1.0f / 512.0f) + EPSV);
    float4 g0 = *(const float4*)(g + lane * 8);
    float4 g1 = *(const float4*)(g + lane * 8 + 4);
    float4 b0 = *(const float4*)(b + lane * 8);
    float4 b1 = *(const float4*)(b + lane * 8 + 4);
    float gg[8] = {g0.x, g0.y, g0.z, g0.w, g1.x, g1.y, g1.z, g1.w};
    float bb[8] = {b0.x, b0.y, b0.z, b0.w, b1.x, b1.y, b1.z, b1.w};
    float x8[8];
    #pragma unroll
    for (int j = 0; j < 8; ++j) x8[j] = fmaxf((e[j] - mu) * inv * gg[j] + bb[j], 0.0f);
    bool needX = false;
    for (int l = 1; l < L; ++l) needX |= (flags[l] == 0);
    if (needX) {
        float* q = Xout + (size_t)r * 512 + lane * 8;
        *(float4*)q = make_float4(x8[0], x8[1], x8[2], x8[3]);
        *(float4*)(q + 4) = make_float4(x8[4], x8[5], x8[6], x8[7]);
    }
    const float s0 = scales[0];
    float rs8[8]; float rn = 0.f;
    #pragma unroll
    for (int j = 0; j < 8; ++j) { rs8[j] = x8[j] * s0; rn += rs8[j] * rs8[j]; }
    #pragma unroll
    for (int off = 1; off < 64; off <<= 1) rn += __shfl_xor(rn, off);
    if (lane == 0) rsn[r] = rn;
    short4 pa, pb;
    pa.x = f2bf(rs8[0]); pa.y = f2bf(rs8[1]); pa.z = f2bf(rs8[2]); pa.w = f2bf(rs8[3]);
    pb.x = f2bf(rs8[4]); pb.y = f2bf(rs8[5]); pb.z = f2bf(rs8[6]); pb.w = f2bf(rs8[7]);
    *(short4*)&plds[wv * 520 + lane * 8] = pa;
    *(short4*)&plds[wv * 520 + lane * 8 + 4] = pb;
    float q8[8], r8[8];
    #pragma unroll
    for (int j = 0; j < 8; ++j) { q8[j] = 0.f; r8[j] = x8[j]; }
    for (int l = 0; l < L; ++l) {
        const float sc = scales[l];
        #pragma unroll
        for (int j = 0; j < 8; ++j) { float rv = r8[j] * sc; q8[j] += rv; r8[j] -= rv / sc; }
    }
    float s2 = 0.f;
    #pragma unroll
    for (int j = 0; j < 8; ++j) s2 += q8[j];
    #pragma unroll
    for (int off = 1; off < 64; off <<= 1) s2 += __shfl_xor(s2, off);
    const float mu2 = s2 * (1.0f / 512.0f);
    float v2 = 0.f;
    #pragma unroll
    for (int j = 0; j < 8; ++j) { float d = q8[j] - mu2; v2 += d * d; }
    #pragma unroll
    for (int off = 1; off < 64; off <<= 1) v2 += __shfl_xor(v2, off);
    const float inv2 = rsqrtf(v2 * (1.0f / 512.0f) + EPSV);
    float* q = outln + (size_t)r * 512 + lane * 8;
    *(float4*)q = make_float4((q8[0] - mu2) * inv2, (q8[1] - mu2) * inv2,
                              (q8[2] - mu2) * inv2, (q8[3] - mu2) * inv2);
    *(float4*)(q + 4) = make_float4((q8[4] - mu2) * inv2, (q8[5] - mu2) * inv2,
                                    (q8[6] - mu2) * inv2, (q8[7] - mu2) * inv2);
    __syncthreads();
    {
        const int t = threadIdx.x;
        const int kb = t >> 2, rr = t & 3;
        int4 v = *(const int4*)&plds[rr * 520 + kb * 8];
        *(int4*)(P1 + ((size_t)kb * M + rb + rr) * 8) = v;
    }
}

// ---------------- dist level 0 (compute-only MFMA, XCD-swizzled rows) ----------------
__global__ __launch_bounds__(256) void dist0_kernel(
    const short* __restrict__ Ap, const short* __restrict__ Bp,
    const float* __restrict__ rsn, const float* __restrict__ cn,
    const float* __restrict__ temp_p, float* __restrict__ out,
    int M, int K, int Kd, int LK) {
    __shared__ __align__(16) short As[8 * 128 * 8];
    __shared__ __align__(16) short Bs[8 * 128 * 8];
    int bx = blockIdx.x; const int nx = gridDim.x;
    if ((nx & 7) == 0) { const int c = nx >> 3; bx = (bx & 7) * c + (bx >> 3); }
    const int r0 = bx * 128;
    const int cl0 = blockIdx.y * 128;     // level-0 columns
    const float inv_t = 1.0f / fmaxf(temp_p[0], TEMP_MINV);
    const int lane = threadIdx.x & 63, w = threadIdx.x >> 6;
    const int wm = (w & 1) << 6, wn = (w >> 1) << 6;
    const int fr = lane & 15, fo = lane >> 4;
    f32x4 acc[4][4];
    #pragma unroll
    for (int a = 0; a < 4; ++a)
        #pragma unroll
        for (int b = 0; b < 4; ++b) acc[a][b] = (f32x4){0.f, 0.f, 0.f, 0.f};
    for (int k0 = 0; k0 < Kd; k0 += 64) {
        const int kb0 = k0 >> 3;
        __syncthreads();
        #pragma unroll
        for (int sidx = 0; sidx < 2; ++sidx) {
            const int kblk = (w << 1) + sidx;
            const short* ga = Ap + ((size_t)(kb0 + kblk) * M + r0) * 8;
            const short* gb = Bp + ((size_t)(kb0 + kblk) * K + cl0) * 8;
            short* la = &As[kblk * 128 * 8];
            short* lb = &Bs[kblk * 128 * 8];
            #pragma unroll
            for (int h = 0; h < 2; ++h) {
                gload16(ga + ((h << 6) + lane) * 8, la + (h << 6) * 8);
                gload16(gb + ((h << 6) + lane) * 8, lb + (h << 6) * 8);
            }
        }
        __syncthreads();
        #pragma unroll
        for (int s = 0; s < 2; ++s) {
            const int kb = (s << 2) + fo;
            bf16x8 af[4], bfv[4];
            #pragma unroll
            for (int mt = 0; mt < 4; ++mt)
                af[mt] = *(const bf16x8*)&As[(kb * 128 + wm + mt * 16 + fr) * 8];
            #pragma unroll
            for (int nt = 0; nt < 4; ++nt)
                bfv[nt] = *(const bf16x8*)&Bs[(kb * 128 + wn + nt * 16 + fr) * 8];
            #pragma unroll
            for (int mt = 0; mt < 4; ++mt)
                #pragma unroll
                for (int nt = 0; nt < 4; ++nt)
                    acc[mt][nt] = __builtin_amdgcn_mfma_f32_16x16x32_bf16(af[mt], bfv[nt], acc[mt][nt], 0, 0, 0);
        }
    }
    #pragma unroll
    for (int mt = 0; mt < 4; ++mt) {
        #pragma unroll
        for (int reg = 0; reg < 4; ++reg) {
            const int r = r0 + wm + mt * 16 + (fo << 2) + reg;
            const float rn = rsn[r];
            float* orow = out + (size_t)r * LK;
            #pragma unroll
            for (int nt = 0; nt < 4; ++nt) {
                const int c = cl0 + wn + nt * 16 + fr;
                orow[c] = -(rn + cn[c] - 2.0f * acc[mt][nt][reg]) * inv_t;
            }
        }
    }
}

// ---------------- gated generic-path prep (levels >=1): pack cb | pack x (recurrence) | rsnorm ----
// lvl_fixed >= 1: single level (sequential fallback, buffers idx 0)
// lvl_fixed < 0 : all levels merged in one launch, per-level buffer sets
__global__ __launch_bounds__(256) void prep_levels(
    const float* __restrict__ x, const float* __restrict__ cb,
    const float* __restrict__ scales, const int* __restrict__ flags,
    short* __restrict__ cbpL, short* __restrict__ P1L, float* __restrict__ rsnL,
    int M, int K, int D, int lvl_fixed) {
    const int nC = K / 32, nX = M / 32;
    const int nPl = nC + nX + M / 4;
    int gid = blockIdx.x, lvl, idx;
    if (lvl_fixed < 0) { lvl = 1 + gid / nPl; idx = lvl - 1; gid -= (lvl - 1) * nPl; }
    else { lvl = lvl_fixed; idx = 0; }
    if (flags[lvl]) return;
    short* cbp = cbpL + (size_t)idx * K * D;
    short* P1  = P1L  + (size_t)idx * M * D;
    float* rsn = rsnL + (size_t)idx * M;
    const float* cb_l = cb + (size_t)lvl * K * D;
    __shared__ __align__(16) short lds[32 * 520];
    if (gid < nC) { pack_block(cb_l, cbp, K, gid * 32, lds); return; }
    gid -= nC;
    if (gid < nX) { pack_block_rec(x, P1, M, gid * 32, lds, scales, lvl); return; }
    gid -= nX;
    const int wv = threadIdx.x >> 6, lane = threadIdx.x & 63;
    const int row = gid * 4 + wv;
    if (row >= M) return;
    const float* p = x + (size_t)row * 512;
    float s = 0.f;
    for (int j = lane; j < 512; j += 64) {
        float r_ = p[j];
        for (int q = 0; q < lvl; ++q) { float sc = scales[q]; float rv = r_ * sc; r_ -= rv / sc; }
        r_ *= scales[lvl];
        s += r_ * r_;
    }
    #pragma unroll
    for (int off = 32; off; off >>= 1) s += __shfl_down(s, off);
    if (lane == 0) rsn[row] = s;
}

// ---------------- gated generic-path dist (levels >=1) ----------------
__global__ __launch_bounds__(256) void distL_kernel(
    const short* __restrict__ P1L, const short* __restrict__ cbpL,
    const float* __restrict__ rsnL, const float* __restrict__ cn,
    const float* __restrict__ temp_p, const int* __restrict__ flags,
    float* __restrict__ out, int M, int K, int Kd, int LK, int lvl_fixed) {
    const int G = K >> 7;
    int lvl, idx, byg;
    if (lvl_fixed < 0) { lvl = 1 + blockIdx.y / G; idx = lvl - 1; byg = blockIdx.y % G; }
    else { lvl = lvl_fixed; idx = 0; byg = blockIdx.y; }
    if (flags[lvl]) return;
    const short* Ap = P1L + (size_t)idx * M * Kd;
    const short* Bp = cbpL + (size_t)idx * K * Kd;
    const float* rsn = rsnL + (size_t)idx * M;
    __shared__ __align__(16) short As[8 * 128 * 8];
    __shared__ __align__(16) short Bs[8 * 128 * 8];
    int bx = blockIdx.x; const int nx = gridDim.x;
    if ((nx & 7) == 0) { const int c = nx >> 3; bx = (bx & 7) * c + (bx >> 3); }
    const int r0 = bx * 128;
    const int cl0 = byg * 128;
    const int cg0 = lvl * K + cl0;
    const float inv_t = 1.0f / fmaxf(temp_p[0], TEMP_MINV);
    const int lane = threadIdx.x & 63, w = threadIdx.x >> 6;
    const int wm = (w & 1) << 6, wn = (w >> 1) << 6;
    const int fr = lane & 15, fo = lane >> 4;
    f32x4 acc[4][4];
    #pragma unroll
    for (int a = 0; a < 4; ++a)
        #pragma unroll
        for (int b = 0; b < 4; ++b) acc[a][b] = (f32x4){0.f, 0.f, 0.f, 0.f};
    for (int k0 = 0; k0 < Kd; k0 += 64) {
        const int kb0 = k0 >> 3;
        __syncthreads();
        #pragma unroll
        for (int sidx = 0; sidx < 2; ++sidx) {
            const int kblk = (w << 1) + sidx;
            const short* ga = Ap + ((size_t)(kb0 + kblk) * M + r0) * 8;
            const short* gb = Bp + ((size_t)(kb0 + kblk) * K + cl0) * 8;
            short* la = &As[kblk * 128 * 8];
            short* lb = &Bs[kblk * 128 * 8];
            #pragma unroll
            for (int h = 0; h < 2; ++h) {
                gload16(ga + ((h << 6) + lane) * 8, la + (h << 6) * 8);
                gload16(gb + ((h << 6) + lane) * 8, lb + (h << 6) * 8);
            }
        }
        __syncthreads();
        #pragma unroll
        for (int s = 0; s < 2; ++s) {
            const int kb = (s << 2) + fo;
            bf16x8 af[4], bfv[4];
            #pragma unroll
            for (int mt = 0; mt < 4; ++mt)
                af[mt] = *(const bf16x8*)&As[(kb * 128 + wm + mt * 16 + fr) * 8];
            #pragma unroll
            for (int nt = 0; nt < 4; ++nt)
                bfv[nt] = *(const bf16x8*)&Bs[(kb * 128 + wn + nt * 16 + fr) * 8];
            #pragma unroll
            for (int mt = 0; mt < 4; ++mt)
                #pragma unroll
                for (int nt = 0; nt < 4; ++nt)
                    acc[mt][nt] = __builtin_amdgcn_mfma_f32_16x16x32_bf16(af[mt], bfv[nt], acc[mt][nt], 0, 0, 0);
        }
    }
    #pragma unroll
    for (int mt = 0; mt < 4; ++mt) {
        #pragma unroll
        for (int reg = 0; reg < 4; ++reg) {
            const int r = r0 + wm + mt * 16 + (fo << 2) + reg;
            const float rn = rsn[r];
            float* orow = out + (size_t)r * LK;
            #pragma unroll
            for (int nt = 0; nt < 4; ++nt) {
                const int c = cg0 + wn + nt * 16 + fr;
                orow[c] = -(rn + cn[c] - 2.0f * acc[mt][nt][reg]) * inv_t;
            }
        }
    }
}

extern "C" void kernel_launch(void* const* d_in, const int* in_sizes, int n_in,
                              void* d_out, int out_size, void* d_ws, size_t ws_size,
                              hipStream_t stream) {
    const float* features = (const float*)d_in[0];
    const float* W        = (const float*)d_in[1];
    const float* bproj    = (const float*)d_in[2];
    const float* lng      = (const float*)d_in[3];
    const float* lnb      = (const float*)d_in[4];
    const float* cb       = (const float*)d_in[5];
    const float* scales   = (const float*)d_in[6];
    const float* temp     = (const float*)d_in[7];

    const int D = in_sizes[2];            // 512
    const int M = in_sizes[0] / D;        // 8192
    const int L = in_sizes[6];            // 4
    const int K = in_sizes[5] / (L * D);  // 2048
    const int LK = L * K;
    const int G = K / 128;

    float* out    = (float*)d_out;                 // [M, L*K]
    float* out_ln = out + (size_t)M * LK;          // [M, D]

    // workspace (floats): x[M*D] | y[M*D] | P1 (M*D bf16) | Wp (D*D bf16) | cbp (K*D bf16)
    //                     | rsn[M] | cn[L*K] | flags(64) | [merged: P1L | cbpL | rsnL per level]
    float* ws = (float*)d_ws;
    float* x  = ws;
    float* y  = x + (size_t)M * D;
    short* P1 = (short*)(y + (size_t)M * D);
    float* aP1 = y + (size_t)M * D + (size_t)M * D / 2;
    short* Wp = (short*)aP1;
    float* aWp = aP1 + (size_t)D * D / 2;
    short* cbp = (short*)aWp;
    float* rsn = aWp + (size_t)K * D / 2;
    float* cn  = rsn + M;
    int* flags = (int*)(cn + (size_t)LK);

    const size_t baseF = (size_t)M * D * 2 + (size_t)M * D / 2 + (size_t)D * D / 2
                       + (size_t)K * D / 2 + (size_t)M + (size_t)LK + 64;
    const size_t extraF = (size_t)(L - 1) * ((size_t)M * D / 2 + (size_t)K * D / 2 + (size_t)M);
    const bool merged = (L > 1) && (ws_size >= (baseF + extraF) * sizeof(float));

    short* P1L; short* cbpL; float* rsnL;
    if (merged) {
        P1L  = (short*)(cn + (size_t)LK + 64);
        cbpL = P1L + (size_t)(L - 1) * M * D;
        rsnL = (float*)(cbpL + (size_t)(L - 1) * K * D);
    } else {
        P1L = P1; cbpL = cbp; rsnL = rsn;   // sequential reuse (safe: dist0 done before)
    }

    flags_kernel<<<1, 64, 0, stream>>>(scales, L, flags);

    // all input packing + codebook norms in one launch
    const int nPrep = M / 32 + D / 32 + K / 32 + (LK + 3) / 4;
    prep_inputs<<<nPrep, 256, 0, stream>>>(features, W, cb, P1, Wp, cbp, cn, M, D, K, LK);

    // y = features @ W^T + b  |  + flagged-level logits broadcast piggyback
    gemm1_mfma<<<dim3(M / 128, D / 128 + (L - 1) * G), 256, 0, stream>>>(
        P1, Wp, bproj, y, cn, temp, flags, out, M, D, D, K, LK);

    // LN+ReLU -> x, rs0 pack -> P1, ||rs0||^2 -> rsn, qsum -> LN -> out_ln
    fused_epi<<<M / 4, 256, 0, stream>>>(y, x, P1, rsn, out_ln, lng, lnb, scales, flags, M, L);

    // level-0 logits (compute-only GEMM)
    dist0_kernel<<<dim3(M / 128, G), 256, 0, stream>>>(P1, cbp, rsn, cn, temp, out, M, K, D, LK);

    // generic path for non-unit scales (no-ops when flagged)
    if (L > 1) {
        const int nPl = K / 32 + M / 32 + M / 4;
        if (merged) {
            prep_levels<<<(L - 1) * nPl, 256, 0, stream>>>(x, cb, scales, flags,
                                                           cbpL, P1L, rsnL, M, K, D, -1);
            distL_kernel<<<dim3(M / 128, (L - 1) * G), 256, 0, stream>>>(
                P1L, cbpL, rsnL, cn, temp, flags, out, M, K, D, LK, -1);
        } else {
            for (int l = 1; l < L; ++l) {
                prep_levels<<<nPl, 256, 0, stream>>>(x, cb, scales, flags,
                                                     cbpL, P1L, rsnL, M, K, D, l);
                distL_kernel<<<dim3(M / 128, G), 256, 0, stream>>>(
                    P1L, cbpL, rsnL, cn, temp, flags, out, M, K, D, LK, l);
            }
        }
    }
}